// Round 1
// baseline (391.492 us; speedup 1.0000x reference)
//
#include <hip/hip_runtime.h>
#include <hip/hip_cooperative_groups.h>
#include <math.h>

namespace cg = cooperative_groups;

// StateSpaceLayer: diagonal SSM scan
//   s_t = a*s_{t-1} + b*u_t ;  y_t = c*s_t + d*u_t ;  a = tanh(logit_a)
// x: (B=8, T=4096, D=1024) fp32, coefs: (D,) fp32, y: (B,T,D) fp32.
//
// Fused single cooperative kernel (was 3 kernels):
//   phase1 : per-chunk local end state (zero init)      -> ws.chunk_end (4 MiB)
//   grid.sync()
//   phase2 : serial per-channel scan over chunk ends    -> ws.chunk_start (4 MiB)
//            (blocks 0..31; same latency as old ssm_prefix but no launch gap)
//   grid.sync()
//   phase3 : load own start state, exact recurrence, write y.
// Same block handles the same chunk in phase1 and phase3 (same CU -> partial
// XCD-L2 hits on the re-read); phase3 walks tasks in reverse of phase1 so the
// most-recently-read chunk is consumed first.
// No ws-init assumptions: every workspace byte is written before it is read.

#define SSM_B 8
#define SSM_T 4096
#define SSM_D 1024
#define SSM_C 128              // chunks
#define SSM_L 32               // chunk length = T / C
#define NTASK (SSM_C * SSM_B)  // 1024 chunk-tasks
#define NBLK 512               // 2 tasks per block; 2 blocks/CU co-resident

typedef float vfloat4 __attribute__((ext_vector_type(4)));

__device__ __forceinline__ float4 f4_fma(float4 a, float4 s, float4 add) {
    return make_float4(fmaf(a.x, s.x, add.x), fmaf(a.y, s.y, add.y),
                       fmaf(a.z, s.z, add.z), fmaf(a.w, s.w, add.w));
}
__device__ __forceinline__ float4 f4_mul(float4 a, float4 b) {
    return make_float4(a.x * b.x, a.y * b.y, a.z * b.z, a.w * b.w);
}
__device__ __forceinline__ void nt_store_f4(float* p, float4 w) {
    vfloat4 v = {w.x, w.y, w.z, w.w};
    __builtin_nontemporal_store(v, (vfloat4*)p);
}
__device__ __forceinline__ float4 nt_load_f4(const float* p) {
    vfloat4 v = __builtin_nontemporal_load((const vfloat4*)p);
    return make_float4(v.x, v.y, v.z, v.w);
}

__global__ __launch_bounds__(256, 2) void ssm_fused(
        const float* __restrict__ x, const float* __restrict__ logit_a,
        const float* __restrict__ bco, const float* __restrict__ cco,
        const float* __restrict__ dco, float* __restrict__ chunk_end,
        float* __restrict__ chunk_start, float* __restrict__ y) {
    const int g  = blockIdx.x;
    const int d4 = threadIdx.x * 4;

    const float4 la = *(const float4*)(logit_a + d4);
    const float4 bv = *(const float4*)(bco + d4);
    const float4 cv = *(const float4*)(cco + d4);
    const float4 dv = *(const float4*)(dco + d4);
    const float4 a  = make_float4(tanhf(la.x), tanhf(la.y), tanhf(la.z), tanhf(la.w));

    // ---- phase 1: per-chunk aggregates (x read from HBM, cached for phase 3)
#pragma unroll
    for (int i = 0; i < 2; ++i) {
        const int tau = g + i * NBLK;          // task id = k*8 + bb
        const int k = tau >> 3, bb = tau & 7;
        const float* xp =
            x + ((size_t)bb * SSM_T + (size_t)k * SSM_L) * SSM_D + d4;
        float4 s = make_float4(0.f, 0.f, 0.f, 0.f);
#pragma unroll 8
        for (int t = 0; t < SSM_L; ++t) {
            float4 u = *(const float4*)(xp + (size_t)t * SSM_D);
            s = f4_fma(a, s, f4_mul(bv, u));
        }
        *(float4*)(chunk_end + (size_t)tau * SSM_D + d4) = s;
    }

    cg::this_grid().sync();

    // ---- phase 2: exclusive scan over chunk ends, one thread per (b, d)
    //   chunk_start[k] = sum_{j<k} a^(L*(k-1-j)) * chunk_end[j]
    if (g < (SSM_B * SSM_D) / 256) {           // 32 blocks, 8192 threads
        const int tid = g * 256 + threadIdx.x; // == bb*1024 + d
        const int d   = tid & (SSM_D - 1);
        float av = tanhf(logit_a[d]);
        float aL = av;
#pragma unroll
        for (int i = 0; i < 5; ++i) aL *= aL;  // a^L, L = 32
        float s = 0.f;
        const size_t stride = (size_t)SSM_B * SSM_D;
        size_t idx = (size_t)tid;
#pragma unroll 4
        for (int j = 0; j < SSM_C; ++j) {
            chunk_start[idx] = s;
            s = fmaf(aL, s, chunk_end[idx]);
            idx += stride;
        }
    }

    cg::this_grid().sync();

    // ---- phase 3: exact recurrence + output (reverse task order: the chunk
    //      read most recently in phase 1 is most likely still in local L2)
#pragma unroll
    for (int i = 1; i >= 0; --i) {
        const int tau = g + i * NBLK;
        const int k = tau >> 3, bb = tau & 7;
        float4 s = *(const float4*)(chunk_start + (size_t)tau * SSM_D + d4);
        const size_t base =
            ((size_t)bb * SSM_T + (size_t)k * SSM_L) * SSM_D + d4;
        const float* xp = x + base;
        float*       yp = y + base;
#pragma unroll 8
        for (int t = 0; t < SSM_L; ++t) {
            float4 u = nt_load_f4(xp + (size_t)t * SSM_D);  // L2/L3 hit
            s = f4_fma(a, s, f4_mul(bv, u));
            float4 w = f4_fma(cv, s, f4_mul(dv, u));
            nt_store_f4(yp + (size_t)t * SSM_D, w);         // write-once, nt
        }
    }
}

extern "C" void kernel_launch(void* const* d_in, const int* in_sizes, int n_in,
                              void* d_out, int out_size, void* d_ws, size_t ws_size,
                              hipStream_t stream) {
    const float* x   = (const float*)d_in[0];
    const float* la  = (const float*)d_in[1];
    const float* bco = (const float*)d_in[2];
    const float* cco = (const float*)d_in[3];
    const float* dco = (const float*)d_in[4];
    float* y = (float*)d_out;
    float* chunk_end   = (float*)d_ws;                                 // 4 MiB
    float* chunk_start = (float*)d_ws + (size_t)NTASK * SSM_D;         // 4 MiB

    void* args[] = {(void*)&x,   (void*)&la,        (void*)&bco,
                    (void*)&cco, (void*)&dco,       (void*)&chunk_end,
                    (void*)&chunk_start, (void*)&y};
    hipLaunchCooperativeKernel((void*)ssm_fused, dim3(NBLK), dim3(256), args,
                               0, stream);
}

// Round 2
// 278.614 us; speedup vs baseline: 1.4051x; 1.4051x over previous
//
#include <hip/hip_runtime.h>
#include <math.h>

// StateSpaceLayer: diagonal SSM scan
//   s_t = a*s_{t-1} + b*u_t ;  y_t = c*s_t + d*u_t ;  a = tanh(logit_a)
// x: (B=8, T=4096, D=1024) fp32, coefs: (D,) fp32, y: (B,T,D) fp32.
//
// Chunked 3-kernel scan (R2: C=256/L=16 for 8 blocks/CU occupancy; coop-fusion
// of R1 regressed: 182us launch overhead + 2-blocks/CU residency cap).
//   pass1 : per-chunk local end state (zero init)      -> ws.chunk_end (8 MiB)
//   prefix: serial per-channel scan over chunk ends    -> ws.chunk_start (8 MiB)
//   pass2 : load own start state, exact recurrence, write y.
// grid = C*B = 2048 blocks of 256 thr -> 8 blocks/CU = 32 waves/CU (HW cap),
// pinned by __launch_bounds__(256, 8) (VGPR<=64; measured 52 on fused R1).
// nt loads for x in pass2 (last use), nt stores for y (don't evict L3-resident x).

#define SSM_B 8
#define SSM_T 4096
#define SSM_D 1024
#define SSM_C 256  // chunks
#define SSM_L 16   // chunk length = T / C  (2^4)

typedef float vfloat4 __attribute__((ext_vector_type(4)));

__device__ __forceinline__ float4 f4_fma(float4 a, float4 s, float4 add) {
    return make_float4(fmaf(a.x, s.x, add.x), fmaf(a.y, s.y, add.y),
                       fmaf(a.z, s.z, add.z), fmaf(a.w, s.w, add.w));
}
__device__ __forceinline__ float4 f4_mul(float4 a, float4 b) {
    return make_float4(a.x * b.x, a.y * b.y, a.z * b.z, a.w * b.w);
}
__device__ __forceinline__ void nt_store_f4(float* p, float4 w) {
    vfloat4 v = {w.x, w.y, w.z, w.w};
    __builtin_nontemporal_store(v, (vfloat4*)p);
}
__device__ __forceinline__ float4 nt_load_f4(const float* p) {
    vfloat4 v = __builtin_nontemporal_load((const vfloat4*)p);
    return make_float4(v.x, v.y, v.z, v.w);
}

__global__ __launch_bounds__(256, 8) void ssm_pass1(
        const float* __restrict__ x, const float* __restrict__ logit_a,
        const float* __restrict__ bco, float* __restrict__ chunk_end) {
    const int k  = blockIdx.x;          // chunk index
    const int bb = blockIdx.y;          // batch index
    const int d4 = threadIdx.x * 4;     // 256 threads cover D=1024

    float4 la = *(const float4*)(logit_a + d4);
    float4 bv = *(const float4*)(bco + d4);
    float4 a  = make_float4(tanhf(la.x), tanhf(la.y), tanhf(la.z), tanhf(la.w));

    float4 s = make_float4(0.f, 0.f, 0.f, 0.f);
    const float* xp = x + ((size_t)bb * SSM_T + (size_t)k * SSM_L) * SSM_D + d4;
#pragma unroll 8
    for (int t = 0; t < SSM_L; ++t) {
        float4 u = *(const float4*)(xp + (size_t)t * SSM_D);
        s = f4_fma(a, s, f4_mul(bv, u));
    }
    *(float4*)(chunk_end + ((size_t)k * SSM_B + bb) * SSM_D + d4) = s;
}

// One scalar thread per (batch, channel): exclusive scan over chunk end-states.
//   chunk_start[k] = sum_{j<k} a^(L*(k-1-j)) * chunk_end[j]
// 8192 threads, 8 MiB read + 8 MiB write, loads independent -> pipelineable.
__global__ __launch_bounds__(256) void ssm_prefix(
        const float* __restrict__ logit_a,
        const float* __restrict__ chunk_end,
        float* __restrict__ chunk_start) {
    const int tid = blockIdx.x * 256 + threadIdx.x;  // [0, B*D)
    const int d   = tid & (SSM_D - 1);

    float a  = tanhf(logit_a[d]);
    float aL = a;
#pragma unroll
    for (int i = 0; i < 4; ++i) aL *= aL;            // a^L, L = 16
    float s = 0.f;
    const size_t stride = (size_t)SSM_B * SSM_D;
    size_t idx = (size_t)tid;                        // tid == bb*D + d
#pragma unroll 8
    for (int j = 0; j < SSM_C; ++j) {
        chunk_start[idx] = s;
        s = fmaf(aL, s, chunk_end[idx]);
        idx += stride;
    }
}

__global__ __launch_bounds__(256, 8) void ssm_pass2(
        const float* __restrict__ x, const float* __restrict__ logit_a,
        const float* __restrict__ bco, const float* __restrict__ cco,
        const float* __restrict__ dco, const float* __restrict__ chunk_start,
        float* __restrict__ y) {
    const int k  = blockIdx.x;
    const int bb = blockIdx.y;
    const int d4 = threadIdx.x * 4;

    float4 la = *(const float4*)(logit_a + d4);
    float4 bv = *(const float4*)(bco + d4);
    float4 cv = *(const float4*)(cco + d4);
    float4 dv = *(const float4*)(dco + d4);
    float4 a  = make_float4(tanhf(la.x), tanhf(la.y), tanhf(la.z), tanhf(la.w));

    // initial state for this chunk: one coalesced 16B load per thread
    float4 s = *(const float4*)(chunk_start + ((size_t)k * SSM_B + bb) * SSM_D + d4);

    const size_t base = ((size_t)bb * SSM_T + (size_t)k * SSM_L) * SSM_D + d4;
    const float* xp = x + base;
    float*       yp = y + base;
#pragma unroll 8
    for (int t = 0; t < SSM_L; ++t) {
        // nt load: last use of x — hit L3 if resident, don't re-pollute
        float4 u = nt_load_f4(xp + (size_t)t * SSM_D);
        s = f4_fma(a, s, f4_mul(bv, u));
        float4 w = f4_fma(cv, s, f4_mul(dv, u));
        // nt store: y is write-once — don't evict L3-resident x
        nt_store_f4(yp + (size_t)t * SSM_D, w);
    }
}

extern "C" void kernel_launch(void* const* d_in, const int* in_sizes, int n_in,
                              void* d_out, int out_size, void* d_ws, size_t ws_size,
                              hipStream_t stream) {
    const float* x   = (const float*)d_in[0];
    const float* la  = (const float*)d_in[1];
    const float* bco = (const float*)d_in[2];
    const float* cco = (const float*)d_in[3];
    const float* dco = (const float*)d_in[4];
    float* y = (float*)d_out;
    float* chunk_end   = (float*)d_ws;                                  // 8 MiB
    float* chunk_start = (float*)d_ws + (size_t)SSM_C * SSM_B * SSM_D;  // 8 MiB

    dim3 grid(SSM_C, SSM_B);           // 2048 blocks -> 8 blocks/CU
    dim3 block(256);
    ssm_pass1<<<grid, block, 0, stream>>>(x, la, bco, chunk_end);
    ssm_prefix<<<dim3((SSM_B * SSM_D) / 256), block, 0, stream>>>(la, chunk_end, chunk_start);
    ssm_pass2<<<grid, block, 0, stream>>>(x, la, bco, cco, dco, chunk_start, y);
}

// Round 3
// 264.718 us; speedup vs baseline: 1.4789x; 1.0525x over previous
//
#include <hip/hip_runtime.h>
#include <math.h>

// StateSpaceLayer: diagonal SSM scan
//   s_t = a*s_{t-1} + b*u_t ;  y_t = c*s_t + d*u_t ;  a = tanh(logit_a)
// x: (B=8, T=4096, D=1024) fp32, coefs: (D,) fp32, y: (B,T,D) fp32.
//
// Chunked 3-kernel scan. R3: explicit load/compute phase split.
//   R1 profile showed phases at 1.3 TB/s, VALUBusy 1.9% — and R2's occupancy
//   doubling (4->8 blocks/CU) was a perf NO-OP. Diagnosis: per-wave
//   outstanding-load count ~1 (compiler interleaved the serial s-chain FMAs
//   with loads + tight waitcnts), so HBM latency is exposed per load.
//   Fix: batch ALL L=16 chunk loads into a statically-indexed register array
//   (16 independent global_load_dwordx4 issued back-to-back), THEN run the
//   dependent FMA chain; pass2 computes y in-place and issues 16 nt stores at
//   the end. Prefix kernel: same trick, 16 chunk_end loads per group.
//   pass1 : per-chunk local end state (zero init)      -> ws.chunk_end (8 MiB)
//   prefix: serial per-channel scan over chunk ends    -> ws.chunk_start (8 MiB)
//   pass2 : load own start state, exact recurrence, write y.

#define SSM_B 8
#define SSM_T 4096
#define SSM_D 1024
#define SSM_C 256  // chunks
#define SSM_L 16   // chunk length = T / C  (fits in regs: 16 float4 = 64 VGPR)

typedef float vfloat4 __attribute__((ext_vector_type(4)));

__device__ __forceinline__ float4 f4_fma(float4 a, float4 s, float4 add) {
    return make_float4(fmaf(a.x, s.x, add.x), fmaf(a.y, s.y, add.y),
                       fmaf(a.z, s.z, add.z), fmaf(a.w, s.w, add.w));
}
__device__ __forceinline__ float4 f4_mul(float4 a, float4 b) {
    return make_float4(a.x * b.x, a.y * b.y, a.z * b.z, a.w * b.w);
}
__device__ __forceinline__ void nt_store_f4(float* p, float4 w) {
    vfloat4 v = {w.x, w.y, w.z, w.w};
    __builtin_nontemporal_store(v, (vfloat4*)p);
}
__device__ __forceinline__ float4 nt_load_f4(const float* p) {
    vfloat4 v = __builtin_nontemporal_load((const vfloat4*)p);
    return make_float4(v.x, v.y, v.z, v.w);
}

__global__ __launch_bounds__(256, 4) void ssm_pass1(
        const float* __restrict__ x, const float* __restrict__ logit_a,
        const float* __restrict__ bco, float* __restrict__ chunk_end) {
    const int k  = blockIdx.x;          // chunk index
    const int bb = blockIdx.y;          // batch index
    const int d4 = threadIdx.x * 4;     // 256 threads cover D=1024

    const float* xp = x + ((size_t)bb * SSM_T + (size_t)k * SSM_L) * SSM_D + d4;

    // ---- load phase: 16 independent 16B loads, no dependent ops between them
    float4 u[SSM_L];
#pragma unroll
    for (int t = 0; t < SSM_L; ++t)
        u[t] = *(const float4*)(xp + (size_t)t * SSM_D);

    float4 la = *(const float4*)(logit_a + d4);
    float4 bv = *(const float4*)(bco + d4);
    float4 a  = make_float4(tanhf(la.x), tanhf(la.y), tanhf(la.z), tanhf(la.w));

    // ---- compute phase: serial FMA chain over registers
    float4 s = make_float4(0.f, 0.f, 0.f, 0.f);
#pragma unroll
    for (int t = 0; t < SSM_L; ++t) s = f4_fma(a, s, f4_mul(bv, u[t]));

    *(float4*)(chunk_end + ((size_t)k * SSM_B + bb) * SSM_D + d4) = s;
}

// One scalar thread per (batch, channel): exclusive scan over chunk end-states.
//   chunk_start[k] = sum_{j<k} a^(L*(k-1-j)) * chunk_end[j]
// Loads batched 16-deep into regs so HBM/L2 latency overlaps.
__global__ __launch_bounds__(128) void ssm_prefix(
        const float* __restrict__ logit_a,
        const float* __restrict__ chunk_end,
        float* __restrict__ chunk_start) {
    const int tid = blockIdx.x * 128 + threadIdx.x;  // [0, B*D)
    const int d   = tid & (SSM_D - 1);

    float a  = tanhf(logit_a[d]);
    float aL = a;
#pragma unroll
    for (int i = 0; i < 4; ++i) aL *= aL;            // a^L, L = 16

    float s = 0.f;
    const size_t stride = (size_t)SSM_B * SSM_D;
    size_t idx = (size_t)tid;                        // tid == bb*D + d
    for (int j0 = 0; j0 < SSM_C; j0 += 16) {
        float ce[16];
#pragma unroll
        for (int i = 0; i < 16; ++i) ce[i] = chunk_end[idx + (size_t)i * stride];
#pragma unroll
        for (int i = 0; i < 16; ++i) {
            chunk_start[idx + (size_t)i * stride] = s;
            s = fmaf(aL, s, ce[i]);
        }
        idx += (size_t)16 * stride;
    }
}

__global__ __launch_bounds__(256, 4) void ssm_pass2(
        const float* __restrict__ x, const float* __restrict__ logit_a,
        const float* __restrict__ bco, const float* __restrict__ cco,
        const float* __restrict__ dco, const float* __restrict__ chunk_start,
        float* __restrict__ y) {
    const int k  = blockIdx.x;
    const int bb = blockIdx.y;
    const int d4 = threadIdx.x * 4;

    const size_t base = ((size_t)bb * SSM_T + (size_t)k * SSM_L) * SSM_D + d4;
    const float* xp = x + base;
    float*       yp = y + base;

    // ---- load phase: 16 independent nt loads (last use of x) + start state
    float4 u[SSM_L];
#pragma unroll
    for (int t = 0; t < SSM_L; ++t) u[t] = nt_load_f4(xp + (size_t)t * SSM_D);
    float4 s = *(const float4*)(chunk_start + ((size_t)k * SSM_B + bb) * SSM_D + d4);

    float4 la = *(const float4*)(logit_a + d4);
    float4 bv = *(const float4*)(bco + d4);
    float4 cv = *(const float4*)(cco + d4);
    float4 dv = *(const float4*)(dco + d4);
    float4 a  = make_float4(tanhf(la.x), tanhf(la.y), tanhf(la.z), tanhf(la.w));

    // ---- compute phase: recurrence; overwrite u[t] with y_t in place
#pragma unroll
    for (int t = 0; t < SSM_L; ++t) {
        s = f4_fma(a, s, f4_mul(bv, u[t]));
        u[t] = f4_fma(cv, s, f4_mul(dv, u[t]));
    }

    // ---- store phase: 16 independent nt stores (write-once y)
#pragma unroll
    for (int t = 0; t < SSM_L; ++t) nt_store_f4(yp + (size_t)t * SSM_D, u[t]);
}

extern "C" void kernel_launch(void* const* d_in, const int* in_sizes, int n_in,
                              void* d_out, int out_size, void* d_ws, size_t ws_size,
                              hipStream_t stream) {
    const float* x   = (const float*)d_in[0];
    const float* la  = (const float*)d_in[1];
    const float* bco = (const float*)d_in[2];
    const float* cco = (const float*)d_in[3];
    const float* dco = (const float*)d_in[4];
    float* y = (float*)d_out;
    float* chunk_end   = (float*)d_ws;                                  // 8 MiB
    float* chunk_start = (float*)d_ws + (size_t)SSM_C * SSM_B * SSM_D;  // 8 MiB

    dim3 grid(SSM_C, SSM_B);           // 2048 blocks -> 8 blocks/CU issued
    dim3 block(256);
    ssm_pass1<<<grid, block, 0, stream>>>(x, la, bco, chunk_end);
    ssm_prefix<<<dim3((SSM_B * SSM_D) / 128), dim3(128), 0, stream>>>(la, chunk_end, chunk_start);
    ssm_pass2<<<grid, block, 0, stream>>>(x, la, bco, cco, dco, chunk_start, y);
}